// Round 6
// baseline (443.275 us; speedup 1.0000x reference)
//
#include <hip/hip_runtime.h>

// Problem constants (match reference setup_inputs)
#define N_NODES 50000
#define N_EDGES 800000
#define F_INF   64
#define C_CH    100
#define T_OUT   8

typedef unsigned short u16;
typedef unsigned int   u32;
typedef __attribute__((ext_vector_type(8))) short bf16x8;
typedef __attribute__((ext_vector_type(4))) float f32x4;

__device__ __forceinline__ float sigmoidf_(float x) {
    return 1.0f / (1.0f + __expf(-x));
}
__device__ __forceinline__ float tanhf_(float x) {
    return 1.0f - 2.0f / (__expf(2.0f * x) + 1.0f);
}
__device__ __forceinline__ u16 f2bf(float f) {
    union { float f; u32 u; } v; v.f = f;
    u32 u = v.u;
    u += 0x7FFF + ((u >> 16) & 1);   // RNE
    return (u16)(u >> 16);
}
__device__ __forceinline__ float bf2f(u16 h) {
    union { u32 u; float f; } v; v.u = ((u32)h) << 16;
    return v.f;
}

// ---------------------------------------------------------------------------
// CSR build stage 1: in-degree histogram (int atomics)
// ---------------------------------------------------------------------------
__global__ void k_hist(const int* __restrict__ ei, int* __restrict__ deg) {
    int e = blockIdx.x * blockDim.x + threadIdx.x;
    if (e >= N_EDGES) return;
    atomicAdd(&deg[ei[N_EDGES + e]], 1);
}

// ---------------------------------------------------------------------------
// CSR build stage 2: exclusive prefix sum over deg -> rowptr, cursor.
// Two-pass (sum, scan totals, re-read + emit) — no per-thread array, no spill.
// ---------------------------------------------------------------------------
#define SCAN_T 1024
#define SCAN_L 49  // ceil(50000/1024)
__global__ __launch_bounds__(SCAN_T) void k_scan(const int* __restrict__ deg,
                                                 int* __restrict__ rowptr,
                                                 int* __restrict__ cursor) {
    __shared__ int s[SCAN_T];
    int t = threadIdx.x;
    int base = t * SCAN_L;
    // pass 1: per-thread chunk total
    int tot = 0;
    for (int j = 0; j < SCAN_L; ++j) {
        int i = base + j;
        if (i < N_NODES) tot += deg[i];
    }
    s[t] = tot;
    __syncthreads();
    // Hillis-Steele inclusive scan over 1024 totals
    for (int off = 1; off < SCAN_T; off <<= 1) {
        int v = (t >= off) ? s[t - off] : 0;
        __syncthreads();
        s[t] += v;
        __syncthreads();
    }
    // pass 2: running prefix, re-reading deg
    int run = s[t] - tot;  // exclusive prefix of this chunk
    for (int j = 0; j < SCAN_L; ++j) {
        int i = base + j;
        if (i < N_NODES) {
            rowptr[i] = run;
            cursor[i] = run;
            run += deg[i];
        }
    }
    if (t == SCAN_T - 1) rowptr[N_NODES] = s[t];
}

// ---------------------------------------------------------------------------
// CSR build stage 3: reorder edges by dst; (src, weight) packed as int2 so
// each edge is ONE 8B random scatter instead of two 4B ones.
// ---------------------------------------------------------------------------
__global__ void k_reorder(const int* __restrict__ ei, const float* __restrict__ ew,
                          int* __restrict__ cursor, int2* __restrict__ edge) {
    int e = blockIdx.x * blockDim.x + threadIdx.x;
    if (e >= N_EDGES) return;
    int s = ei[e];
    int d = ei[N_EDGES + e];
    int pos = atomicAdd(&cursor[d], 1);
    union { float f; int i; } w; w.f = ew[e];
    edge[pos] = make_int2(s, w.i);
}

// ---------------------------------------------------------------------------
// x -> bf16 (for the gather phase: halves random-gather traffic)
// ---------------------------------------------------------------------------
__global__ void k_xbf(const float* __restrict__ x, u16* __restrict__ xbf) {
    int idx = blockIdx.x * blockDim.x + threadIdx.x;
    if (idx >= N_NODES * F_INF / 8) return;
    float4 a = ((const float4*)x)[idx * 2];
    float4 b = ((const float4*)x)[idx * 2 + 1];
    uint4 p;
    p.x = (u32)f2bf(a.x) | ((u32)f2bf(a.y) << 16);
    p.y = (u32)f2bf(a.z) | ((u32)f2bf(a.w) << 16);
    p.z = (u32)f2bf(b.x) | ((u32)f2bf(b.y) << 16);
    p.w = (u32)f2bf(b.z) | ((u32)f2bf(b.w) << 16);
    ((uint4*)xbf)[idx] = p;
}

// ---------------------------------------------------------------------------
// Aggregate: wave per node, lane = channel.  bf16 x rows (128B/edge gather),
// edge metadata broadcast as single int2.  2x unroll for MLP.
// ---------------------------------------------------------------------------
__global__ __launch_bounds__(256) void k_agg(
    const int* __restrict__ rowptr, const int2* __restrict__ edge,
    const u16* __restrict__ xbf, u16* __restrict__ xaggbf) {
    int node = blockIdx.x * 4 + (threadIdx.x >> 6);
    int lane = threadIdx.x & 63;
    if (node >= N_NODES) return;
    int e0 = rowptr[node];
    int e1 = rowptr[node + 1];
    float acc = 0.0f;
    int e = e0;
    for (; e + 1 < e1; e += 2) {
        int2 ed0 = edge[e];
        int2 ed1 = edge[e + 1];
        union { int i; float f; } w0, w1;
        w0.i = ed0.y; w1.i = ed1.y;
        acc += bf2f(xbf[(size_t)ed0.x * F_INF + lane]) * w0.f;
        acc += bf2f(xbf[(size_t)ed1.x * F_INF + lane]) * w1.f;
    }
    if (e < e1) {
        int2 ed = edge[e];
        union { int i; float f; } w; w.i = ed.y;
        acc += bf2f(xbf[(size_t)ed.x * F_INF + lane]) * w.f;
    }
    acc /= fmaxf((float)(e1 - e0), 1.0f);
    xaggbf[(size_t)node * F_INF + lane] = f2bf(acc);
}

// ---------------------------------------------------------------------------
// Weight prep (GRU + LSTM in one launch).
// Wgru[4][112][128]: g in {r,z,i_n,h_n}; k<64: (gwih@ggc^T) (g<3); k>=64: gwhh.
// Wl[4][64][192]: k<100 lwih; 100..127 zero; 128..191 lwhh.
// ---------------------------------------------------------------------------
#define WGRU_ELEMS (4 * 112 * 128)
#define WL_ELEMS   (4 * 64 * 192)
__global__ void k_wprep(const float* __restrict__ ggc, const float* __restrict__ gwih,
                        const float* __restrict__ gwhh,
                        const float* __restrict__ lwih, const float* __restrict__ lwhh,
                        u16* __restrict__ Wgru, u16* __restrict__ Wl) {
    int idx = blockIdx.x * blockDim.x + threadIdx.x;
    if (idx < WGRU_ELEMS) {
        int g = idx / 14336;
        int r = idx - g * 14336;
        int c = r >> 7;
        int k = r & 127;
        float val = 0.0f;
        if (c < 100) {
            if (g < 3) {
                if (k < 64) {
                    const float* wr = gwih + (g * 100 + c) * 100;
                    const float* gr = ggc + k * 100;
                    float s = 0.0f;
#pragma unroll 4
                    for (int j = 0; j < 100; ++j) s += wr[j] * gr[j];
                    val = s;
                } else if (g < 2) {
                    val = gwhh[(g * 100 + c) * 100 + (k - 64)];
                }
            } else {
                if (k >= 64) val = gwhh[(200 + c) * 100 + (k - 64)];
            }
        }
        Wgru[idx] = f2bf(val);
    } else if (idx < WGRU_ELEMS + WL_ELEMS) {
        int i2 = idx - WGRU_ELEMS;
        int g = i2 / 12288;
        int r = i2 - g * 12288;
        int c = r / 192;
        int k = r - c * 192;
        int row = g * 64 + c;
        float val = 0.0f;
        if (k < 100) val = lwih[row * 100 + k];
        else if (k >= 128) val = lwhh[row * 64 + (k - 128)];
        Wl[i2] = f2bf(val);
    }
}

// ---------------------------------------------------------------------------
// Fused GRU + LSTM + head via MFMA bf16.  Block = 256 thr (4 waves), 64 nodes.
// Wave-ct specialization: each weight byte loaded once per block.
// A1 stride 152 u16 (19 x 16B chunks, 3 mod 8 -> conflict-free b128).
// A2 stride 216 u16 (27 chunks, 3 mod 8).
// ---------------------------------------------------------------------------
#define A1S 152
#define A2S 216
__global__ __launch_bounds__(256, 3) void k_fused(
    const u16* __restrict__ xaggbf, const float* __restrict__ x,
    const float* __restrict__ h0, const float* __restrict__ c0,
    const u16* __restrict__ Wgru, const u16* __restrict__ Wl,
    const float* __restrict__ gbih, const float* __restrict__ gbhh,
    const float* __restrict__ lbih, const float* __restrict__ lbhh,
    const float* __restrict__ lw, const float* __restrict__ lb,
    float* __restrict__ out, float* __restrict__ h1, float* __restrict__ c1) {
    __shared__ char smem[52608];
    u16*   A1   = (u16*)(smem);
    u16*   A2   = (u16*)(smem + 19456);
    float* bias = (float*)(smem + 47104);
    float* bl   = (float*)(smem + 49504);
    float* lwf  = (float*)(smem + 50528);   // [k*8+t]
    float* lbs  = (float*)(smem + 52576);
    int tid = threadIdx.x;
    int n0 = blockIdx.x * 64;

    // ---- stage A1 cols 0..63: xagg bf16 ----
    for (int idx = tid; idx < 512; idx += 256) {
        int row = idx >> 3, ch = idx & 7;
        int n = n0 + row;
        uint4 v = make_uint4(0, 0, 0, 0);
        if (n < N_NODES) v = ((const uint4*)xaggbf)[n * 8 + ch];
        *(uint4*)(A1 + row * A1S + ch * 8) = v;
    }
    // ---- stage A1 cols 64..127: x fp32 -> bf16 ----
    for (int idx = tid; idx < 512; idx += 256) {
        int row = idx >> 3, ch = idx & 7;
        int n = n0 + row;
        uint4 p = make_uint4(0, 0, 0, 0);
        if (n < N_NODES) {
            float4 f0 = ((const float4*)x)[n * 16 + ch * 2];
            float4 f1 = ((const float4*)x)[n * 16 + ch * 2 + 1];
            p.x = (u32)f2bf(f0.x) | ((u32)f2bf(f0.y) << 16);
            p.y = (u32)f2bf(f0.z) | ((u32)f2bf(f0.w) << 16);
            p.z = (u32)f2bf(f1.x) | ((u32)f2bf(f1.y) << 16);
            p.w = (u32)f2bf(f1.z) | ((u32)f2bf(f1.w) << 16);
        }
        *(uint4*)(A1 + row * A1S + 64 + ch * 8) = p;
    }
    // ---- stage A2 cols 128..191: h0 fp32 -> bf16 ----
    for (int idx = tid; idx < 512; idx += 256) {
        int row = idx >> 3, ch = idx & 7;
        int n = n0 + row;
        uint4 p = make_uint4(0, 0, 0, 0);
        if (n < N_NODES) {
            float4 f0 = ((const float4*)h0)[n * 16 + ch * 2];
            float4 f1 = ((const float4*)h0)[n * 16 + ch * 2 + 1];
            p.x = (u32)f2bf(f0.x) | ((u32)f2bf(f0.y) << 16);
            p.y = (u32)f2bf(f0.z) | ((u32)f2bf(f0.w) << 16);
            p.z = (u32)f2bf(f1.x) | ((u32)f2bf(f1.y) << 16);
            p.w = (u32)f2bf(f1.z) | ((u32)f2bf(f1.w) << 16);
        }
        *(uint4*)(A2 + row * A2S + 128 + ch * 8) = p;
    }
    // ---- zero A2 cols 100..127 ----
    for (int idx = tid; idx < 64 * 14; idx += 256) {
        int row = idx / 14, j = idx - row * 14;
        *(u32*)((char*)A2 + row * (A2S * 2) + 200 + j * 4) = 0;
    }
    // ---- biases + head weights ----
    for (int idx = tid; idx < 600; idx += 256)
        bias[idx] = (idx < 300) ? gbih[idx] : gbhh[idx - 300];
    if (tid < 256) bl[tid] = lbih[tid] + lbhh[tid];
    for (int idx = tid; idx < 512; idx += 256) {
        int k = idx >> 3, t = idx & 7;
        lwf[idx] = lw[t * F_INF + k];
    }
    if (tid < 8) lbs[tid] = lb[tid];
    __syncthreads();

    int w = tid >> 6, lane = tid & 63, quad = lane >> 4, ln = lane & 15;

    // ================= GEMM1: GRU gates, wave handles ct = w, w+4 =========
    for (int ct = w; ct < 7; ct += 4) {
        f32x4 ar[4], az[4], an[4], ah[4];
#pragma unroll
        for (int mt = 0; mt < 4; ++mt) {
            ar[mt] = (f32x4){0.f, 0.f, 0.f, 0.f};
            az[mt] = ar[mt]; an[mt] = ar[mt]; ah[mt] = ar[mt];
        }
        int rb = (ct * 16 + ln) * 128 + quad * 8;
#pragma unroll
        for (int kt = 0; kt < 4; ++kt) {
            bf16x8 b0 = *(const bf16x8*)(Wgru + rb + kt * 32);
            bf16x8 b1 = *(const bf16x8*)(Wgru + 14336 + rb + kt * 32);
            bf16x8 b2 = *(const bf16x8*)(Wgru + 2 * 14336 + rb + kt * 32);
            bf16x8 b3 = *(const bf16x8*)(Wgru + 3 * 14336 + rb + kt * 32);
#pragma unroll
            for (int mt = 0; mt < 4; ++mt) {
                bf16x8 a = *(const bf16x8*)(A1 + (mt * 16 + ln) * A1S + kt * 32 + quad * 8);
                ar[mt] = __builtin_amdgcn_mfma_f32_16x16x32_bf16(a, b0, ar[mt], 0, 0, 0);
                az[mt] = __builtin_amdgcn_mfma_f32_16x16x32_bf16(a, b1, az[mt], 0, 0, 0);
                an[mt] = __builtin_amdgcn_mfma_f32_16x16x32_bf16(a, b2, an[mt], 0, 0, 0);
                ah[mt] = __builtin_amdgcn_mfma_f32_16x16x32_bf16(a, b3, ah[mt], 0, 0, 0);
            }
        }
        int c = ct * 16 + ln;
        if (c < 100) {
            float br = bias[c] + bias[300 + c];
            float bz = bias[100 + c] + bias[400 + c];
            float bn = bias[200 + c];
            float bh = bias[500 + c];
#pragma unroll
            for (int mt = 0; mt < 4; ++mt) {
#pragma unroll
                for (int reg = 0; reg < 4; ++reg) {
                    int m = mt * 16 + quad * 4 + reg;
                    float rv = sigmoidf_(ar[mt][reg] + br);
                    float zv = sigmoidf_(az[mt][reg] + bz);
                    float nv = tanhf_(an[mt][reg] + bn + rv * (ah[mt][reg] + bh));
                    float xp = (c < F_INF) ? bf2f(A1[m * A1S + 64 + c]) : 0.0f;
                    A2[m * A2S + c] = f2bf((1.0f - zv) * nv + zv * xp);
                }
            }
        }
    }
    __syncthreads();

    // ================= GEMM2: LSTM gates, wave handles ct = w =============
    float h1v[4][4], c1v[4][4];
    {
        int ct = w;  // 0..3
        f32x4 ai[4], af[4], ag[4], ao[4];
#pragma unroll
        for (int mt = 0; mt < 4; ++mt) {
            ai[mt] = (f32x4){0.f, 0.f, 0.f, 0.f};
            af[mt] = ai[mt]; ag[mt] = ai[mt]; ao[mt] = ai[mt];
        }
        int rb = (ct * 16 + ln) * 192 + quad * 8;
#pragma unroll
        for (int kt = 0; kt < 6; ++kt) {
            bf16x8 b0 = *(const bf16x8*)(Wl + rb + kt * 32);
            bf16x8 b1 = *(const bf16x8*)(Wl + 12288 + rb + kt * 32);
            bf16x8 b2 = *(const bf16x8*)(Wl + 2 * 12288 + rb + kt * 32);
            bf16x8 b3 = *(const bf16x8*)(Wl + 3 * 12288 + rb + kt * 32);
#pragma unroll
            for (int mt = 0; mt < 4; ++mt) {
                bf16x8 a = *(const bf16x8*)(A2 + (mt * 16 + ln) * A2S + kt * 32 + quad * 8);
                ai[mt] = __builtin_amdgcn_mfma_f32_16x16x32_bf16(a, b0, ai[mt], 0, 0, 0);
                af[mt] = __builtin_amdgcn_mfma_f32_16x16x32_bf16(a, b1, af[mt], 0, 0, 0);
                ag[mt] = __builtin_amdgcn_mfma_f32_16x16x32_bf16(a, b2, ag[mt], 0, 0, 0);
                ao[mt] = __builtin_amdgcn_mfma_f32_16x16x32_bf16(a, b3, ao[mt], 0, 0, 0);
            }
        }
        int c = ct * 16 + ln;  // < 64
        float bi = bl[c], bff = bl[64 + c], bg = bl[128 + c], bo = bl[192 + c];
#pragma unroll
        for (int mt = 0; mt < 4; ++mt) {
#pragma unroll
            for (int reg = 0; reg < 4; ++reg) {
                int m = mt * 16 + quad * 4 + reg;
                int n = n0 + m;
                float iv = sigmoidf_(ai[mt][reg] + bi);
                float fv = sigmoidf_(af[mt][reg] + bff);
                float gv = tanhf_(ag[mt][reg] + bg);
                float ov = sigmoidf_(ao[mt][reg] + bo);
                float c0v = (n < N_NODES) ? c0[(size_t)n * F_INF + c] : 0.0f;
                float cc = fv * c0v + iv * gv;
                c1v[mt][reg] = cc;
                h1v[mt][reg] = ov * tanhf_(cc);
            }
        }
    }
    __syncthreads();   // A1/A2 dead; scratch overlay begins

    float* h1s = (float*)smem;             // [64][68]
    float* c1s = (float*)(smem + 17408);   // [64][68]
    {
        int c = w * 16 + ln;
#pragma unroll
        for (int mt = 0; mt < 4; ++mt) {
#pragma unroll
            for (int reg = 0; reg < 4; ++reg) {
                int m = mt * 16 + quad * 4 + reg;
                h1s[m * 68 + c] = h1v[mt][reg];
                c1s[m * 68 + c] = c1v[mt][reg];
            }
        }
    }
    __syncthreads();

    // ---- fused head: out[n,t] = relu(h1[n,:]) @ lw^T + lb ----
    for (int o = tid; o < 512; o += 256) {
        int nl = o >> 3, t = o & 7;
        float acc = lbs[t];
        const float* hr = h1s + nl * 68;
#pragma unroll 8
        for (int k = 0; k < F_INF; ++k)
            acc += fmaxf(hr[k], 0.0f) * lwf[k * 8 + t];
        int n = n0 + nl;
        if (n < N_NODES) out[(size_t)n * T_OUT + t] = acc;
    }
    // ---- coalesced h1/c1 stores ----
    for (int idx = tid; idx < 64 * 16; idx += 256) {
        int row = idx >> 4, c4 = idx & 15;
        int n = n0 + row;
        if (n < N_NODES) {
            ((float4*)h1)[n * 16 + c4] = *(float4*)(h1s + row * 68 + c4 * 4);
            ((float4*)c1)[n * 16 + c4] = *(float4*)(c1s + row * 68 + c4 * 4);
        }
    }
}

extern "C" void kernel_launch(void* const* d_in, const int* in_sizes, int n_in,
                              void* d_out, int out_size, void* d_ws, size_t ws_size,
                              hipStream_t stream) {
    const float* x     = (const float*)d_in[0];
    const int*   ei    = (const int*)d_in[1];
    const float* ew    = (const float*)d_in[2];
    const float* h0    = (const float*)d_in[3];
    const float* c0    = (const float*)d_in[4];
    const float* ggc   = (const float*)d_in[5];
    const float* gwih  = (const float*)d_in[6];
    const float* gwhh  = (const float*)d_in[7];
    const float* gbih  = (const float*)d_in[8];
    const float* gbhh  = (const float*)d_in[9];
    const float* lwih  = (const float*)d_in[10];
    const float* lwhh  = (const float*)d_in[11];
    const float* lbih  = (const float*)d_in[12];
    const float* lbhh  = (const float*)d_in[13];
    const float* lw    = (const float*)d_in[14];
    const float* lb    = (const float*)d_in[15];

    float* out = (float*)d_out;                  // [N, 8]
    float* h1  = out + (size_t)N_NODES * T_OUT;  // [N, 64]
    float* c1  = h1 + (size_t)N_NODES * F_INF;   // [N, 64]

    // workspace layout (bytes; all 16B aligned)
    char* ws = (char*)d_ws;
    u16*   xaggbf = (u16*)ws;                                  // N*64 u16 = 6.4MB
    u16*   xbf    = (u16*)(ws + 6400000);                      // N*64 u16 = 6.4MB
    u16*   Wgru   = (u16*)(ws + 12800000);                     // 114688 B
    u16*   Wl     = (u16*)(ws + 12914688);                     // 98304 B
    int2*  edge   = (int2*)(ws + 13013056);                    // E*8 = 6.4MB (16B aligned)
    int*   deg    = (int*)(ws + 13013056 + 6400000);           // N
    int*   rowptr = deg + N_NODES;                             // N+1
    int*   cursor = rowptr + N_NODES + 1;                      // N

    hipMemsetAsync(deg, 0, N_NODES * sizeof(int), stream);

    { int b = (N_EDGES + 255) / 256;
      k_hist<<<b, 256, 0, stream>>>(ei, deg); }
    { int b = (N_NODES * F_INF / 8 + 255) / 256;
      k_xbf<<<b, 256, 0, stream>>>(x, xbf); }
    k_scan<<<1, SCAN_T, 0, stream>>>(deg, rowptr, cursor);
    { int b = (N_EDGES + 255) / 256;
      k_reorder<<<b, 256, 0, stream>>>(ei, ew, cursor, edge); }
    { int b = (N_NODES + 3) / 4;  // wave per node
      k_agg<<<b, 256, 0, stream>>>(rowptr, edge, xbf, xaggbf); }
    { int b = (WGRU_ELEMS + WL_ELEMS + 255) / 256;
      k_wprep<<<b, 256, 0, stream>>>(ggc, gwih, gwhh, lwih, lwhh, Wgru, Wl); }
    { int b = (N_NODES + 63) / 64;  // 782
      k_fused<<<b, 256, 0, stream>>>(xaggbf, x, h0, c0, Wgru, Wl,
                                     gbih, gbhh, lbih, lbhh, lw, lb,
                                     out, h1, c1); }
}

// Round 7
// 361.270 us; speedup vs baseline: 1.2270x; 1.2270x over previous
//
#include <hip/hip_runtime.h>

// Problem constants (match reference setup_inputs)
#define N_NODES 50000
#define N_EDGES 800000
#define F_INF   64
#define C_CH    100
#define T_OUT   8

typedef unsigned short u16;
typedef unsigned int   u32;
typedef __attribute__((ext_vector_type(8))) short bf16x8;
typedef __attribute__((ext_vector_type(4))) float f32x4;

__device__ __forceinline__ float sigmoidf_(float x) {
    return 1.0f / (1.0f + __expf(-x));
}
__device__ __forceinline__ float tanhf_(float x) {
    return 1.0f - 2.0f / (__expf(2.0f * x) + 1.0f);
}
__device__ __forceinline__ u16 f2bf(float f) {
    union { float f; u32 u; } v; v.f = f;
    u32 u = v.u;
    u += 0x7FFF + ((u >> 16) & 1);   // RNE
    return (u16)(u >> 16);
}
__device__ __forceinline__ float bf2f(u16 h) {
    union { u32 u; float f; } v; v.u = ((u32)h) << 16;
    return v.f;
}

// ---------------------------------------------------------------------------
// CSR build stage 1: in-degree histogram (int atomics)
// ---------------------------------------------------------------------------
__global__ void k_hist(const int* __restrict__ ei, int* __restrict__ deg) {
    int e = blockIdx.x * blockDim.x + threadIdx.x;
    if (e >= N_EDGES) return;
    atomicAdd(&deg[ei[N_EDGES + e]], 1);
}

// ---------------------------------------------------------------------------
// CSR build stage 2: exclusive prefix sum over deg -> rowptr, cursor.
// LDS-staged: coalesced int4 global loads into a 100KB LDS tile (x2 tiles),
// per-thread chunk scan from LDS (stride 49 = odd -> conflict-free),
// Hillis-Steele over 1024 chunk totals, restage, emit with running register.
// No per-thread arrays (no spill), no uncoalesced global reads.
// ---------------------------------------------------------------------------
#define SCAN_T 1024
#define SCAN_L 49               // elements per thread chunk
#define TILE   (512 * SCAN_L)   // 25088 elements = 100352 B LDS
__global__ __launch_bounds__(SCAN_T) void k_scan(const int* __restrict__ deg,
                                                 int* __restrict__ rowptr,
                                                 int* __restrict__ cursor) {
    __shared__ int ld[TILE];
    __shared__ int s[SCAN_T];
    const int4* deg4 = (const int4*)deg;   // N_NODES = 50000 = 12500 int4s
    int4* ld4 = (int4*)ld;
    int t = threadIdx.x;

    // ---- pass 1, tile 0: elements [0, TILE) ----
    for (int i = t; i < TILE / 4; i += SCAN_T) ld4[i] = deg4[i];  // 6272 int4 < 12500
    __syncthreads();
    int tot = 0;
    if (t < 512) {
        int base = t * SCAN_L;
#pragma unroll 7
        for (int j = 0; j < SCAN_L; ++j) tot += ld[base + j];
    }
    __syncthreads();
    // ---- pass 1, tile 1: elements [TILE, 2*TILE) ----
    for (int i = t; i < TILE / 4; i += SCAN_T) {
        int g4 = TILE / 4 + i;   // 6272..12543
        ld4[i] = (g4 < N_NODES / 4) ? deg4[g4] : make_int4(0, 0, 0, 0);
    }
    __syncthreads();
    if (t >= 512) {
        int base = (t - 512) * SCAN_L;
#pragma unroll 7
        for (int j = 0; j < SCAN_L; ++j) tot += ld[base + j];
    }
    s[t] = tot;
    __syncthreads();
    // ---- Hillis-Steele inclusive scan over 1024 totals ----
    for (int off = 1; off < SCAN_T; off <<= 1) {
        int v = (t >= off) ? s[t - off] : 0;
        __syncthreads();
        s[t] += v;
        __syncthreads();
    }
    int run = s[t] - tot;   // exclusive prefix of this thread's chunk

    // ---- pass 2, tile 0 ----
    for (int i = t; i < TILE / 4; i += SCAN_T) ld4[i] = deg4[i];
    __syncthreads();
    if (t < 512) {
        int base = t * SCAN_L;
        for (int j = 0; j < SCAN_L; ++j) {
            int i = base + j;
            rowptr[i] = run;
            cursor[i] = run;
            run += ld[base + j];
        }
    }
    __syncthreads();
    // ---- pass 2, tile 1 ----
    for (int i = t; i < TILE / 4; i += SCAN_T) {
        int g4 = TILE / 4 + i;
        ld4[i] = (g4 < N_NODES / 4) ? deg4[g4] : make_int4(0, 0, 0, 0);
    }
    __syncthreads();
    if (t >= 512) {
        int base = (t - 512) * SCAN_L;
        for (int j = 0; j < SCAN_L; ++j) {
            int g = TILE + base + j;
            if (g < N_NODES) {
                rowptr[g] = run;
                cursor[g] = run;
                run += ld[base + j];
            }
        }
    }
    if (t == SCAN_T - 1) rowptr[N_NODES] = s[t];
}

// ---------------------------------------------------------------------------
// CSR build stage 3: reorder edges by dst; (src, weight) packed as int2 so
// each edge is ONE 8B random scatter instead of two 4B ones.
// ---------------------------------------------------------------------------
__global__ void k_reorder(const int* __restrict__ ei, const float* __restrict__ ew,
                          int* __restrict__ cursor, int2* __restrict__ edge) {
    int e = blockIdx.x * blockDim.x + threadIdx.x;
    if (e >= N_EDGES) return;
    int s = ei[e];
    int d = ei[N_EDGES + e];
    int pos = atomicAdd(&cursor[d], 1);
    union { float f; int i; } w; w.f = ew[e];
    edge[pos] = make_int2(s, w.i);
}

// ---------------------------------------------------------------------------
// x -> bf16 (for the gather phase: halves random-gather traffic)
// ---------------------------------------------------------------------------
__global__ void k_xbf(const float* __restrict__ x, u16* __restrict__ xbf) {
    int idx = blockIdx.x * blockDim.x + threadIdx.x;
    if (idx >= N_NODES * F_INF / 8) return;
    float4 a = ((const float4*)x)[idx * 2];
    float4 b = ((const float4*)x)[idx * 2 + 1];
    uint4 p;
    p.x = (u32)f2bf(a.x) | ((u32)f2bf(a.y) << 16);
    p.y = (u32)f2bf(a.z) | ((u32)f2bf(a.w) << 16);
    p.z = (u32)f2bf(b.x) | ((u32)f2bf(b.y) << 16);
    p.w = (u32)f2bf(b.z) | ((u32)f2bf(b.w) << 16);
    ((uint4*)xbf)[idx] = p;
}

// ---------------------------------------------------------------------------
// Aggregate: wave per node, lane = channel.  bf16 x rows (128B/edge gather),
// edge metadata broadcast as single int2.  2x unroll for ILP.
// ---------------------------------------------------------------------------
__global__ __launch_bounds__(256) void k_agg(
    const int* __restrict__ rowptr, const int2* __restrict__ edge,
    const u16* __restrict__ xbf, u16* __restrict__ xaggbf) {
    int node = blockIdx.x * 4 + (threadIdx.x >> 6);
    int lane = threadIdx.x & 63;
    if (node >= N_NODES) return;
    int e0 = rowptr[node];
    int e1 = rowptr[node + 1];
    float acc = 0.0f;
    int e = e0;
    for (; e + 1 < e1; e += 2) {
        int2 ed0 = edge[e];
        int2 ed1 = edge[e + 1];
        union { int i; float f; } w0, w1;
        w0.i = ed0.y; w1.i = ed1.y;
        acc += bf2f(xbf[(size_t)ed0.x * F_INF + lane]) * w0.f;
        acc += bf2f(xbf[(size_t)ed1.x * F_INF + lane]) * w1.f;
    }
    if (e < e1) {
        int2 ed = edge[e];
        union { int i; float f; } w; w.i = ed.y;
        acc += bf2f(xbf[(size_t)ed.x * F_INF + lane]) * w.f;
    }
    acc /= fmaxf((float)(e1 - e0), 1.0f);
    xaggbf[(size_t)node * F_INF + lane] = f2bf(acc);
}

// ---------------------------------------------------------------------------
// Weight prep (GRU + LSTM in one launch).
// Wgru[4][112][128]: g in {r,z,i_n,h_n}; k<64: (gwih@ggc^T) (g<3); k>=64: gwhh.
// Wl[4][64][192]: k<100 lwih; 100..127 zero; 128..191 lwhh.
// ---------------------------------------------------------------------------
#define WGRU_ELEMS (4 * 112 * 128)
#define WL_ELEMS   (4 * 64 * 192)
__global__ void k_wprep(const float* __restrict__ ggc, const float* __restrict__ gwih,
                        const float* __restrict__ gwhh,
                        const float* __restrict__ lwih, const float* __restrict__ lwhh,
                        u16* __restrict__ Wgru, u16* __restrict__ Wl) {
    int idx = blockIdx.x * blockDim.x + threadIdx.x;
    if (idx < WGRU_ELEMS) {
        int g = idx / 14336;
        int r = idx - g * 14336;
        int c = r >> 7;
        int k = r & 127;
        float val = 0.0f;
        if (c < 100) {
            if (g < 3) {
                if (k < 64) {
                    const float* wr = gwih + (g * 100 + c) * 100;
                    const float* gr = ggc + k * 100;
                    float s = 0.0f;
#pragma unroll 4
                    for (int j = 0; j < 100; ++j) s += wr[j] * gr[j];
                    val = s;
                } else if (g < 2) {
                    val = gwhh[(g * 100 + c) * 100 + (k - 64)];
                }
            } else {
                if (k >= 64) val = gwhh[(200 + c) * 100 + (k - 64)];
            }
        }
        Wgru[idx] = f2bf(val);
    } else if (idx < WGRU_ELEMS + WL_ELEMS) {
        int i2 = idx - WGRU_ELEMS;
        int g = i2 / 12288;
        int r = i2 - g * 12288;
        int c = r / 192;
        int k = r - c * 192;
        int row = g * 64 + c;
        float val = 0.0f;
        if (k < 100) val = lwih[row * 100 + k];
        else if (k >= 128) val = lwhh[row * 64 + (k - 128)];
        Wl[i2] = f2bf(val);
    }
}

// ---------------------------------------------------------------------------
// Fused GRU + LSTM + head via MFMA bf16.  Block = 256 thr (4 waves), 64 nodes.
// Wave-ct specialization: each weight byte loaded once per block.
// A1 stride 152 u16 (19 x 16B chunks, 3 mod 8 -> conflict-free b128).
// A2 stride 216 u16 (27 chunks, 3 mod 8).
// ---------------------------------------------------------------------------
#define A1S 152
#define A2S 216
__global__ __launch_bounds__(256, 3) void k_fused(
    const u16* __restrict__ xaggbf, const float* __restrict__ x,
    const float* __restrict__ h0, const float* __restrict__ c0,
    const u16* __restrict__ Wgru, const u16* __restrict__ Wl,
    const float* __restrict__ gbih, const float* __restrict__ gbhh,
    const float* __restrict__ lbih, const float* __restrict__ lbhh,
    const float* __restrict__ lw, const float* __restrict__ lb,
    float* __restrict__ out, float* __restrict__ h1, float* __restrict__ c1) {
    __shared__ char smem[52608];
    u16*   A1   = (u16*)(smem);
    u16*   A2   = (u16*)(smem + 19456);
    float* bias = (float*)(smem + 47104);
    float* bl   = (float*)(smem + 49504);
    float* lwf  = (float*)(smem + 50528);   // [k*8+t]
    float* lbs  = (float*)(smem + 52576);
    int tid = threadIdx.x;
    int n0 = blockIdx.x * 64;

    // ---- stage A1 cols 0..63: xagg bf16 ----
    for (int idx = tid; idx < 512; idx += 256) {
        int row = idx >> 3, ch = idx & 7;
        int n = n0 + row;
        uint4 v = make_uint4(0, 0, 0, 0);
        if (n < N_NODES) v = ((const uint4*)xaggbf)[n * 8 + ch];
        *(uint4*)(A1 + row * A1S + ch * 8) = v;
    }
    // ---- stage A1 cols 64..127: x fp32 -> bf16 ----
    for (int idx = tid; idx < 512; idx += 256) {
        int row = idx >> 3, ch = idx & 7;
        int n = n0 + row;
        uint4 p = make_uint4(0, 0, 0, 0);
        if (n < N_NODES) {
            float4 f0 = ((const float4*)x)[n * 16 + ch * 2];
            float4 f1 = ((const float4*)x)[n * 16 + ch * 2 + 1];
            p.x = (u32)f2bf(f0.x) | ((u32)f2bf(f0.y) << 16);
            p.y = (u32)f2bf(f0.z) | ((u32)f2bf(f0.w) << 16);
            p.z = (u32)f2bf(f1.x) | ((u32)f2bf(f1.y) << 16);
            p.w = (u32)f2bf(f1.z) | ((u32)f2bf(f1.w) << 16);
        }
        *(uint4*)(A1 + row * A1S + 64 + ch * 8) = p;
    }
    // ---- stage A2 cols 128..191: h0 fp32 -> bf16 ----
    for (int idx = tid; idx < 512; idx += 256) {
        int row = idx >> 3, ch = idx & 7;
        int n = n0 + row;
        uint4 p = make_uint4(0, 0, 0, 0);
        if (n < N_NODES) {
            float4 f0 = ((const float4*)h0)[n * 16 + ch * 2];
            float4 f1 = ((const float4*)h0)[n * 16 + ch * 2 + 1];
            p.x = (u32)f2bf(f0.x) | ((u32)f2bf(f0.y) << 16);
            p.y = (u32)f2bf(f0.z) | ((u32)f2bf(f0.w) << 16);
            p.z = (u32)f2bf(f1.x) | ((u32)f2bf(f1.y) << 16);
            p.w = (u32)f2bf(f1.z) | ((u32)f2bf(f1.w) << 16);
        }
        *(uint4*)(A2 + row * A2S + 128 + ch * 8) = p;
    }
    // ---- zero A2 cols 100..127 ----
    for (int idx = tid; idx < 64 * 14; idx += 256) {
        int row = idx / 14, j = idx - row * 14;
        *(u32*)((char*)A2 + row * (A2S * 2) + 200 + j * 4) = 0;
    }
    // ---- biases + head weights ----
    for (int idx = tid; idx < 600; idx += 256)
        bias[idx] = (idx < 300) ? gbih[idx] : gbhh[idx - 300];
    if (tid < 256) bl[tid] = lbih[tid] + lbhh[tid];
    for (int idx = tid; idx < 512; idx += 256) {
        int k = idx >> 3, t = idx & 7;
        lwf[idx] = lw[t * F_INF + k];
    }
    if (tid < 8) lbs[tid] = lb[tid];
    __syncthreads();

    int w = tid >> 6, lane = tid & 63, quad = lane >> 4, ln = lane & 15;

    // ================= GEMM1: GRU gates, wave handles ct = w, w+4 =========
    for (int ct = w; ct < 7; ct += 4) {
        f32x4 ar[4], az[4], an[4], ah[4];
#pragma unroll
        for (int mt = 0; mt < 4; ++mt) {
            ar[mt] = (f32x4){0.f, 0.f, 0.f, 0.f};
            az[mt] = ar[mt]; an[mt] = ar[mt]; ah[mt] = ar[mt];
        }
        int rb = (ct * 16 + ln) * 128 + quad * 8;
#pragma unroll
        for (int kt = 0; kt < 4; ++kt) {
            bf16x8 b0 = *(const bf16x8*)(Wgru + rb + kt * 32);
            bf16x8 b1 = *(const bf16x8*)(Wgru + 14336 + rb + kt * 32);
            bf16x8 b2 = *(const bf16x8*)(Wgru + 2 * 14336 + rb + kt * 32);
            bf16x8 b3 = *(const bf16x8*)(Wgru + 3 * 14336 + rb + kt * 32);
#pragma unroll
            for (int mt = 0; mt < 4; ++mt) {
                bf16x8 a = *(const bf16x8*)(A1 + (mt * 16 + ln) * A1S + kt * 32 + quad * 8);
                ar[mt] = __builtin_amdgcn_mfma_f32_16x16x32_bf16(a, b0, ar[mt], 0, 0, 0);
                az[mt] = __builtin_amdgcn_mfma_f32_16x16x32_bf16(a, b1, az[mt], 0, 0, 0);
                an[mt] = __builtin_amdgcn_mfma_f32_16x16x32_bf16(a, b2, an[mt], 0, 0, 0);
                ah[mt] = __builtin_amdgcn_mfma_f32_16x16x32_bf16(a, b3, ah[mt], 0, 0, 0);
            }
        }
        int c = ct * 16 + ln;
        if (c < 100) {
            float br = bias[c] + bias[300 + c];
            float bz = bias[100 + c] + bias[400 + c];
            float bn = bias[200 + c];
            float bh = bias[500 + c];
#pragma unroll
            for (int mt = 0; mt < 4; ++mt) {
#pragma unroll
                for (int reg = 0; reg < 4; ++reg) {
                    int m = mt * 16 + quad * 4 + reg;
                    float rv = sigmoidf_(ar[mt][reg] + br);
                    float zv = sigmoidf_(az[mt][reg] + bz);
                    float nv = tanhf_(an[mt][reg] + bn + rv * (ah[mt][reg] + bh));
                    float xp = (c < F_INF) ? bf2f(A1[m * A1S + 64 + c]) : 0.0f;
                    A2[m * A2S + c] = f2bf((1.0f - zv) * nv + zv * xp);
                }
            }
        }
    }
    __syncthreads();

    // ================= GEMM2: LSTM gates, wave handles ct = w =============
    float h1v[4][4], c1v[4][4];
    {
        int ct = w;  // 0..3
        f32x4 ai[4], af[4], ag[4], ao[4];
#pragma unroll
        for (int mt = 0; mt < 4; ++mt) {
            ai[mt] = (f32x4){0.f, 0.f, 0.f, 0.f};
            af[mt] = ai[mt]; ag[mt] = ai[mt]; ao[mt] = ai[mt];
        }
        int rb = (ct * 16 + ln) * 192 + quad * 8;
#pragma unroll
        for (int kt = 0; kt < 6; ++kt) {
            bf16x8 b0 = *(const bf16x8*)(Wl + rb + kt * 32);
            bf16x8 b1 = *(const bf16x8*)(Wl + 12288 + rb + kt * 32);
            bf16x8 b2 = *(const bf16x8*)(Wl + 2 * 12288 + rb + kt * 32);
            bf16x8 b3 = *(const bf16x8*)(Wl + 3 * 12288 + rb + kt * 32);
#pragma unroll
            for (int mt = 0; mt < 4; ++mt) {
                bf16x8 a = *(const bf16x8*)(A2 + (mt * 16 + ln) * A2S + kt * 32 + quad * 8);
                ai[mt] = __builtin_amdgcn_mfma_f32_16x16x32_bf16(a, b0, ai[mt], 0, 0, 0);
                af[mt] = __builtin_amdgcn_mfma_f32_16x16x32_bf16(a, b1, af[mt], 0, 0, 0);
                ag[mt] = __builtin_amdgcn_mfma_f32_16x16x32_bf16(a, b2, ag[mt], 0, 0, 0);
                ao[mt] = __builtin_amdgcn_mfma_f32_16x16x32_bf16(a, b3, ao[mt], 0, 0, 0);
            }
        }
        int c = ct * 16 + ln;  // < 64
        float bi = bl[c], bff = bl[64 + c], bg = bl[128 + c], bo = bl[192 + c];
#pragma unroll
        for (int mt = 0; mt < 4; ++mt) {
#pragma unroll
            for (int reg = 0; reg < 4; ++reg) {
                int m = mt * 16 + quad * 4 + reg;
                int n = n0 + m;
                float iv = sigmoidf_(ai[mt][reg] + bi);
                float fv = sigmoidf_(af[mt][reg] + bff);
                float gv = tanhf_(ag[mt][reg] + bg);
                float ov = sigmoidf_(ao[mt][reg] + bo);
                float c0v = (n < N_NODES) ? c0[(size_t)n * F_INF + c] : 0.0f;
                float cc = fv * c0v + iv * gv;
                c1v[mt][reg] = cc;
                h1v[mt][reg] = ov * tanhf_(cc);
            }
        }
    }
    __syncthreads();   // A1/A2 dead; scratch overlay begins

    float* h1s = (float*)smem;             // [64][68]
    float* c1s = (float*)(smem + 17408);   // [64][68]
    {
        int c = w * 16 + ln;
#pragma unroll
        for (int mt = 0; mt < 4; ++mt) {
#pragma unroll
            for (int reg = 0; reg < 4; ++reg) {
                int m = mt * 16 + quad * 4 + reg;
                h1s[m * 68 + c] = h1v[mt][reg];
                c1s[m * 68 + c] = c1v[mt][reg];
            }
        }
    }
    __syncthreads();

    // ---- fused head: out[n,t] = relu(h1[n,:]) @ lw^T + lb ----
    for (int o = tid; o < 512; o += 256) {
        int nl = o >> 3, t = o & 7;
        float acc = lbs[t];
        const float* hr = h1s + nl * 68;
#pragma unroll 8
        for (int k = 0; k < F_INF; ++k)
            acc += fmaxf(hr[k], 0.0f) * lwf[k * 8 + t];
        int n = n0 + nl;
        if (n < N_NODES) out[(size_t)n * T_OUT + t] = acc;
    }
    // ---- coalesced h1/c1 stores ----
    for (int idx = tid; idx < 64 * 16; idx += 256) {
        int row = idx >> 4, c4 = idx & 15;
        int n = n0 + row;
        if (n < N_NODES) {
            ((float4*)h1)[n * 16 + c4] = *(float4*)(h1s + row * 68 + c4 * 4);
            ((float4*)c1)[n * 16 + c4] = *(float4*)(c1s + row * 68 + c4 * 4);
        }
    }
}

extern "C" void kernel_launch(void* const* d_in, const int* in_sizes, int n_in,
                              void* d_out, int out_size, void* d_ws, size_t ws_size,
                              hipStream_t stream) {
    const float* x     = (const float*)d_in[0];
    const int*   ei    = (const int*)d_in[1];
    const float* ew    = (const float*)d_in[2];
    const float* h0    = (const float*)d_in[3];
    const float* c0    = (const float*)d_in[4];
    const float* ggc   = (const float*)d_in[5];
    const float* gwih  = (const float*)d_in[6];
    const float* gwhh  = (const float*)d_in[7];
    const float* gbih  = (const float*)d_in[8];
    const float* gbhh  = (const float*)d_in[9];
    const float* lwih  = (const float*)d_in[10];
    const float* lwhh  = (const float*)d_in[11];
    const float* lbih  = (const float*)d_in[12];
    const float* lbhh  = (const float*)d_in[13];
    const float* lw    = (const float*)d_in[14];
    const float* lb    = (const float*)d_in[15];

    float* out = (float*)d_out;                  // [N, 8]
    float* h1  = out + (size_t)N_NODES * T_OUT;  // [N, 64]
    float* c1  = h1 + (size_t)N_NODES * F_INF;   // [N, 64]

    // workspace layout (bytes; all 16B aligned)
    char* ws = (char*)d_ws;
    u16*   xaggbf = (u16*)ws;                                  // N*64 u16 = 6.4MB
    u16*   xbf    = (u16*)(ws + 6400000);                      // N*64 u16 = 6.4MB
    u16*   Wgru   = (u16*)(ws + 12800000);                     // 114688 B
    u16*   Wl     = (u16*)(ws + 12914688);                     // 98304 B
    int2*  edge   = (int2*)(ws + 13013056);                    // E*8 = 6.4MB (16B aligned)
    int*   deg    = (int*)(ws + 13013056 + 6400000);           // N (16B aligned)
    int*   rowptr = deg + N_NODES;                             // N+1
    int*   cursor = rowptr + N_NODES + 1;                      // N

    hipMemsetAsync(deg, 0, N_NODES * sizeof(int), stream);

    { int b = (N_EDGES + 255) / 256;
      k_hist<<<b, 256, 0, stream>>>(ei, deg); }
    { int b = (N_NODES * F_INF / 8 + 255) / 256;
      k_xbf<<<b, 256, 0, stream>>>(x, xbf); }
    k_scan<<<1, SCAN_T, 0, stream>>>(deg, rowptr, cursor);
    { int b = (N_EDGES + 255) / 256;
      k_reorder<<<b, 256, 0, stream>>>(ei, ew, cursor, edge); }
    { int b = (N_NODES + 3) / 4;  // wave per node
      k_agg<<<b, 256, 0, stream>>>(rowptr, edge, xbf, xaggbf); }
    { int b = (WGRU_ELEMS + WL_ELEMS + 255) / 256;
      k_wprep<<<b, 256, 0, stream>>>(ggc, gwih, gwhh, lwih, lwhh, Wgru, Wl); }
    { int b = (N_NODES + 63) / 64;  // 782
      k_fused<<<b, 256, 0, stream>>>(xaggbf, x, h0, c0, Wgru, Wl,
                                     gbih, gbhh, lbih, lbhh, lw, lb,
                                     out, h1, c1); }
}

// Round 8
// 358.766 us; speedup vs baseline: 1.2356x; 1.0070x over previous
//
#include <hip/hip_runtime.h>

// Problem constants (match reference setup_inputs)
#define N_NODES 50000
#define N_EDGES 800000
#define F_INF   64
#define C_CH    100
#define T_OUT   8

typedef unsigned short u16;
typedef unsigned int   u32;
typedef __attribute__((ext_vector_type(8))) short bf16x8;
typedef __attribute__((ext_vector_type(4))) float f32x4;

__device__ __forceinline__ float sigmoidf_(float x) {
    return 1.0f / (1.0f + __expf(-x));
}
__device__ __forceinline__ float tanhf_(float x) {
    return 1.0f - 2.0f / (__expf(2.0f * x) + 1.0f);
}
__device__ __forceinline__ u16 f2bf(float f) {
    union { float f; u32 u; } v; v.f = f;
    u32 u = v.u;
    u += 0x7FFF + ((u >> 16) & 1);   // RNE
    return (u16)(u >> 16);
}
__device__ __forceinline__ float bf2f(u16 h) {
    union { u32 u; float f; } v; v.u = ((u32)h) << 16;
    return v.f;
}
__device__ __forceinline__ float asf_(int i) {
    union { int i; float f; } v; v.i = i; return v.f;
}

// ---------------------------------------------------------------------------
// k_prep: fused (a) in-degree histogram, (b) x->bf16, (c) weight prep.
// Independent work split by block ranges.
// Wgru padded to [4][128][128] so GEMM1 B-loads never go OOB.
// ---------------------------------------------------------------------------
#define HIST_B 3125                     // 800000/256
#define XBF_B  1563                     // ceil(400000/256)
#define WGRU_ELEMS (4 * 128 * 128)      // 65536 (rows padded 112->128)
#define WL_ELEMS   (4 * 64 * 192)       // 49152
#define WP_B  ((WGRU_ELEMS + WL_ELEMS + 255) / 256)   // 448
__global__ void k_prep(const int* __restrict__ ei, const float* __restrict__ x,
                       const float* __restrict__ ggc, const float* __restrict__ gwih,
                       const float* __restrict__ gwhh,
                       const float* __restrict__ lwih, const float* __restrict__ lwhh,
                       int* __restrict__ deg, u16* __restrict__ xbf,
                       u16* __restrict__ Wgru, u16* __restrict__ Wl) {
    int gb = blockIdx.x;
    if (gb < HIST_B) {
        int e = gb * 256 + threadIdx.x;
        if (e < N_EDGES) atomicAdd(&deg[ei[N_EDGES + e]], 1);
        return;
    }
    if (gb < HIST_B + XBF_B) {
        int idx = (gb - HIST_B) * 256 + threadIdx.x;
        if (idx >= N_NODES * F_INF / 8) return;
        float4 a = ((const float4*)x)[idx * 2];
        float4 b = ((const float4*)x)[idx * 2 + 1];
        uint4 p;
        p.x = (u32)f2bf(a.x) | ((u32)f2bf(a.y) << 16);
        p.y = (u32)f2bf(a.z) | ((u32)f2bf(a.w) << 16);
        p.z = (u32)f2bf(b.x) | ((u32)f2bf(b.y) << 16);
        p.w = (u32)f2bf(b.z) | ((u32)f2bf(b.w) << 16);
        ((uint4*)xbf)[idx] = p;
        return;
    }
    int idx = (gb - HIST_B - XBF_B) * 256 + threadIdx.x;
    if (idx < WGRU_ELEMS) {
        int g = idx >> 14;         // gate
        int r = idx & 16383;
        int c = r >> 7;            // 0..127 (valid < 100)
        int k = r & 127;
        float val = 0.0f;
        if (c < 100) {
            if (g < 3) {
                if (k < 64) {
                    const float* wr = gwih + (g * 100 + c) * 100;
                    const float* gr = ggc + k * 100;
                    float s = 0.0f;
#pragma unroll 4
                    for (int j = 0; j < 100; ++j) s += wr[j] * gr[j];
                    val = s;
                } else if (g < 2) {
                    val = gwhh[(g * 100 + c) * 100 + (k - 64)];
                }
            } else {
                if (k >= 64) val = gwhh[(200 + c) * 100 + (k - 64)];
            }
        }
        Wgru[idx] = f2bf(val);
    } else if (idx < WGRU_ELEMS + WL_ELEMS) {
        int i2 = idx - WGRU_ELEMS;
        int g = i2 / 12288;
        int r = i2 - g * 12288;
        int c = r / 192;
        int k = r - c * 192;
        int row = g * 64 + c;
        float val = 0.0f;
        if (k < 100) val = lwih[row * 100 + k];
        else if (k >= 128) val = lwhh[row * 64 + (k - 128)];
        Wl[i2] = f2bf(val);
    }
}

// ---------------------------------------------------------------------------
// CSR stage 2: exclusive prefix sum, LDS-staged (coalesced int4 loads),
// no per-thread arrays.
// ---------------------------------------------------------------------------
#define SCAN_T 1024
#define SCAN_L 49
#define TILE   (512 * SCAN_L)   // 25088 elems
__global__ __launch_bounds__(SCAN_T) void k_scan(const int* __restrict__ deg,
                                                 int* __restrict__ rowptr,
                                                 int* __restrict__ cursor) {
    __shared__ int ld[TILE];
    __shared__ int s[SCAN_T];
    const int4* deg4 = (const int4*)deg;
    int4* ld4 = (int4*)ld;
    int t = threadIdx.x;

    for (int i = t; i < TILE / 4; i += SCAN_T) ld4[i] = deg4[i];
    __syncthreads();
    int tot = 0;
    if (t < 512) {
        int base = t * SCAN_L;
#pragma unroll 7
        for (int j = 0; j < SCAN_L; ++j) tot += ld[base + j];
    }
    __syncthreads();
    for (int i = t; i < TILE / 4; i += SCAN_T) {
        int g4 = TILE / 4 + i;
        ld4[i] = (g4 < N_NODES / 4) ? deg4[g4] : make_int4(0, 0, 0, 0);
    }
    __syncthreads();
    if (t >= 512) {
        int base = (t - 512) * SCAN_L;
#pragma unroll 7
        for (int j = 0; j < SCAN_L; ++j) tot += ld[base + j];
    }
    s[t] = tot;
    __syncthreads();
    for (int off = 1; off < SCAN_T; off <<= 1) {
        int v = (t >= off) ? s[t - off] : 0;
        __syncthreads();
        s[t] += v;
        __syncthreads();
    }
    int run = s[t] - tot;

    for (int i = t; i < TILE / 4; i += SCAN_T) ld4[i] = deg4[i];
    __syncthreads();
    if (t < 512) {
        int base = t * SCAN_L;
        for (int j = 0; j < SCAN_L; ++j) {
            int i = base + j;
            rowptr[i] = run;
            cursor[i] = run;
            run += ld[base + j];
        }
    }
    __syncthreads();
    for (int i = t; i < TILE / 4; i += SCAN_T) {
        int g4 = TILE / 4 + i;
        ld4[i] = (g4 < N_NODES / 4) ? deg4[g4] : make_int4(0, 0, 0, 0);
    }
    __syncthreads();
    if (t >= 512) {
        int base = (t - 512) * SCAN_L;
        for (int j = 0; j < SCAN_L; ++j) {
            int g = TILE + base + j;
            if (g < N_NODES) {
                rowptr[g] = run;
                cursor[g] = run;
                run += ld[base + j];
            }
        }
    }
    if (t == SCAN_T - 1) rowptr[N_NODES] = s[t];
}

// ---------------------------------------------------------------------------
// CSR stage 3: reorder, 2 edges per thread (independent chains for MLP).
// ---------------------------------------------------------------------------
#define HALF_E (N_EDGES / 2)
__global__ void k_reorder(const int* __restrict__ ei, const float* __restrict__ ew,
                          int* __restrict__ cursor, int2* __restrict__ edge) {
    int t = blockIdx.x * blockDim.x + threadIdx.x;
    if (t >= HALF_E) return;
    int e0 = t, e1 = t + HALF_E;
    int s0 = ei[e0], s1 = ei[e1];
    int d0 = ei[N_EDGES + e0], d1 = ei[N_EDGES + e1];
    float w0 = ew[e0], w1 = ew[e1];
    int p0 = atomicAdd(&cursor[d0], 1);
    int p1 = atomicAdd(&cursor[d1], 1);
    union { float f; int i; } a, b; a.f = w0; b.f = w1;
    edge[p0] = make_int2(s0, a.i);
    edge[p1] = make_int2(s1, b.i);
}

// ---------------------------------------------------------------------------
// Aggregate: wave per node, lane = channel (u16 row gathers, 128B/edge).
// int4 metadata loads (2 edges each), 4-edge unroll -> 4 gathers in flight.
// ---------------------------------------------------------------------------
__global__ __launch_bounds__(256) void k_agg(
    const int* __restrict__ rowptr, const int2* __restrict__ edge,
    const u16* __restrict__ xbf, u16* __restrict__ xaggbf) {
    int node = blockIdx.x * 4 + (threadIdx.x >> 6);
    int lane = threadIdx.x & 63;
    if (node >= N_NODES) return;
    int e0 = rowptr[node];
    int e1 = rowptr[node + 1];
    float acc = 0.0f;
    int e = e0;
    if ((e & 1) && e < e1) {   // align for int4 loads
        int2 ed = edge[e];
        acc += bf2f(xbf[(size_t)ed.x * F_INF + lane]) * asf_(ed.y);
        ++e;
    }
    for (; e + 3 < e1; e += 4) {
        int4 p0 = *(const int4*)(edge + e);
        int4 p1 = *(const int4*)(edge + e + 2);
        float v0 = bf2f(xbf[(size_t)p0.x * F_INF + lane]);
        float v1 = bf2f(xbf[(size_t)p0.z * F_INF + lane]);
        float v2 = bf2f(xbf[(size_t)p1.x * F_INF + lane]);
        float v3 = bf2f(xbf[(size_t)p1.z * F_INF + lane]);
        acc += v0 * asf_(p0.y);
        acc += v1 * asf_(p0.w);
        acc += v2 * asf_(p1.y);
        acc += v3 * asf_(p1.w);
    }
    for (; e < e1; ++e) {
        int2 ed = edge[e];
        acc += bf2f(xbf[(size_t)ed.x * F_INF + lane]) * asf_(ed.y);
    }
    acc /= fmaxf((float)(e1 - e0), 1.0f);
    xaggbf[(size_t)node * F_INF + lane] = f2bf(acc);
}

// ---------------------------------------------------------------------------
// Fused GRU + LSTM + head via MFMA bf16.  Block = 256 thr (4 waves), 64 nodes.
// GEMM1 A-fragments loaded DIRECTLY from global (xaggbf/xbf are contiguous
// 16B chunks in exactly A-frag layout) -> no A1 LDS, no staging conflicts.
// A2 (conv_h | pad | h0) in LDS for the GEMM1->GEMM2 layout round trip.
// h1/c1 stored to global straight from accumulators (C-layout, 64B segments).
// Head reads h1 via LDS overlay with stride 65 + nl-major loop (2-way free).
// LDS: A2 @0 (27648) | bias @27648 (2400) | bl @30048 (1024) |
//      lwf @31072 (2048) | lbs @33120 (32)  => 33152 B -> 4 blocks/CU.
// Overlay after GEMM2: h1s float[64][65] @0 (16640 B, clears lwf/lbs).
// ---------------------------------------------------------------------------
#define A2S 216
__global__ __launch_bounds__(256, 4) void k_fused(
    const u16* __restrict__ xaggbf, const u16* __restrict__ xbf,
    const float* __restrict__ h0, const float* __restrict__ c0,
    const u16* __restrict__ Wgru, const u16* __restrict__ Wl,
    const float* __restrict__ gbih, const float* __restrict__ gbhh,
    const float* __restrict__ lbih, const float* __restrict__ lbhh,
    const float* __restrict__ lw, const float* __restrict__ lb,
    float* __restrict__ out, float* __restrict__ h1, float* __restrict__ c1) {
    __shared__ char smem[33152];
    u16*   A2   = (u16*)smem;
    float* bias = (float*)(smem + 27648);
    float* bl   = (float*)(smem + 30048);
    float* lwf  = (float*)(smem + 31072);   // [k*8+t]
    float* lbs  = (float*)(smem + 33120);
    int tid = threadIdx.x;
    int n0 = blockIdx.x * 64;

    // ---- stage A2 cols 128..191: h0 fp32 -> bf16 ----
    for (int idx = tid; idx < 512; idx += 256) {
        int row = idx >> 3, ch = idx & 7;
        int n = n0 + row;
        uint4 p = make_uint4(0, 0, 0, 0);
        if (n < N_NODES) {
            float4 f0 = ((const float4*)h0)[n * 16 + ch * 2];
            float4 f1 = ((const float4*)h0)[n * 16 + ch * 2 + 1];
            p.x = (u32)f2bf(f0.x) | ((u32)f2bf(f0.y) << 16);
            p.y = (u32)f2bf(f0.z) | ((u32)f2bf(f0.w) << 16);
            p.z = (u32)f2bf(f1.x) | ((u32)f2bf(f1.y) << 16);
            p.w = (u32)f2bf(f1.z) | ((u32)f2bf(f1.w) << 16);
        }
        *(uint4*)((char*)A2 + row * 432 + 256 + ch * 16) = p;
    }
    // ---- zero A2 cols 100..127 ----
    for (int idx = tid; idx < 64 * 14; idx += 256) {
        int row = idx / 14, j = idx - row * 14;
        *(u32*)((char*)A2 + row * 432 + 200 + j * 4) = 0;
    }
    // ---- biases + head weights ----
    for (int idx = tid; idx < 600; idx += 256)
        bias[idx] = (idx < 300) ? gbih[idx] : gbhh[idx - 300];
    if (tid < 256) bl[tid] = lbih[tid] + lbhh[tid];
    for (int idx = tid; idx < 512; idx += 256) {
        int k = idx >> 3, t = idx & 7;
        lwf[idx] = lw[t * F_INF + k];
    }
    if (tid < 8) lbs[tid] = lb[tid];
    __syncthreads();

    int w = tid >> 6, lane = tid & 63, quad = lane >> 4, ln = lane & 15;

    // ================= GEMM1: GRU gates (A-frags direct from global) ======
    for (int ci = 0; ci < 2; ++ci) {
        int ct = w + ci * 4;
        if (ct >= 7) continue;           // tiles 0..6
        int c = ct * 16 + ln;
        float br = 0.f, bz = 0.f, bn = 0.f, bh = 0.f;
        if (c < 100) {
            br = bias[c] + bias[300 + c];
            bz = bias[100 + c] + bias[400 + c];
            bn = bias[200 + c];
            bh = bias[500 + c];
        }
        const u16* Bb = Wgru + (ct * 16 + ln) * 128 + quad * 8;  // padded 128 rows
        for (int mp = 0; mp < 2; ++mp) {
            f32x4 ar[2], az[2], an[2], ah[2];
#pragma unroll
            for (int m2 = 0; m2 < 2; ++m2) {
                ar[m2] = (f32x4){0.f, 0.f, 0.f, 0.f};
                az[m2] = ar[m2]; an[m2] = ar[m2]; ah[m2] = ar[m2];
            }
#pragma unroll
            for (int kt = 0; kt < 4; ++kt) {
                bf16x8 b0 = *(const bf16x8*)(Bb + kt * 32);
                bf16x8 b1 = *(const bf16x8*)(Bb + 16384 + kt * 32);
                bf16x8 b2 = *(const bf16x8*)(Bb + 32768 + kt * 32);
                bf16x8 b3 = *(const bf16x8*)(Bb + 49152 + kt * 32);
#pragma unroll
                for (int m2 = 0; m2 < 2; ++m2) {
                    int an_ = min(n0 + (mp * 2 + m2) * 16 + ln, N_NODES - 1);
                    bf16x8 a = (kt < 2)
                        ? *(const bf16x8*)(xaggbf + (size_t)an_ * 64 + kt * 32 + quad * 8)
                        : *(const bf16x8*)(xbf + (size_t)an_ * 64 + (kt - 2) * 32 + quad * 8);
                    ar[m2] = __builtin_amdgcn_mfma_f32_16x16x32_bf16(a, b0, ar[m2], 0, 0, 0);
                    az[m2] = __builtin_amdgcn_mfma_f32_16x16x32_bf16(a, b1, az[m2], 0, 0, 0);
                    an[m2] = __builtin_amdgcn_mfma_f32_16x16x32_bf16(a, b2, an[m2], 0, 0, 0);
                    ah[m2] = __builtin_amdgcn_mfma_f32_16x16x32_bf16(a, b3, ah[m2], 0, 0, 0);
                }
            }
            if (c < 100) {
#pragma unroll
                for (int m2 = 0; m2 < 2; ++m2) {
#pragma unroll
                    for (int reg = 0; reg < 4; ++reg) {
                        int m = (mp * 2 + m2) * 16 + quad * 4 + reg;
                        float rv = sigmoidf_(ar[m2][reg] + br);
                        float zv = sigmoidf_(az[m2][reg] + bz);
                        float nv = tanhf_(an[m2][reg] + bn + rv * (ah[m2][reg] + bh));
                        float xp = 0.0f;
                        if (c < F_INF) {
                            int nn_ = min(n0 + m, N_NODES - 1);
                            xp = bf2f(xbf[(size_t)nn_ * 64 + c]);
                        }
                        A2[m * A2S + c] = f2bf((1.0f - zv) * nv + zv * xp);
                    }
                }
            }
        }
    }
    __syncthreads();

    // ================= GEMM2: LSTM gates + epilogue + direct stores =======
    float h1v[2][2][4];
    {
        int ct = w;                       // 0..3
        int c = ct * 16 + ln;             // < 64
        float bi = bl[c], bff = bl[64 + c], bg = bl[128 + c], bo = bl[192 + c];
        const u16* Bb = Wl + (ct * 16 + ln) * 192 + quad * 8;
        for (int mp = 0; mp < 2; ++mp) {
            f32x4 ai[2], af[2], ag[2], ao[2];
#pragma unroll
            for (int m2 = 0; m2 < 2; ++m2) {
                ai[m2] = (f32x4){0.f, 0.f, 0.f, 0.f};
                af[m2] = ai[m2]; ag[m2] = ai[m2]; ao[m2] = ai[m2];
            }
#pragma unroll
            for (int kt = 0; kt < 6; ++kt) {
                bf16x8 b0 = *(const bf16x8*)(Bb + kt * 32);
                bf16x8 b1 = *(const bf16x8*)(Bb + 12288 + kt * 32);
                bf16x8 b2 = *(const bf16x8*)(Bb + 2 * 12288 + kt * 32);
                bf16x8 b3 = *(const bf16x8*)(Bb + 3 * 12288 + kt * 32);
#pragma unroll
                for (int m2 = 0; m2 < 2; ++m2) {
                    bf16x8 a = *(const bf16x8*)(A2 + ((mp * 2 + m2) * 16 + ln) * A2S
                                                + kt * 32 + quad * 8);
                    ai[m2] = __builtin_amdgcn_mfma_f32_16x16x32_bf16(a, b0, ai[m2], 0, 0, 0);
                    af[m2] = __builtin_amdgcn_mfma_f32_16x16x32_bf16(a, b1, af[m2], 0, 0, 0);
                    ag[m2] = __builtin_amdgcn_mfma_f32_16x16x32_bf16(a, b2, ag[m2], 0, 0, 0);
                    ao[m2] = __builtin_amdgcn_mfma_f32_16x16x32_bf16(a, b3, ao[m2], 0, 0, 0);
                }
            }
#pragma unroll
            for (int m2 = 0; m2 < 2; ++m2) {
#pragma unroll
                for (int reg = 0; reg < 4; ++reg) {
                    int m = (mp * 2 + m2) * 16 + quad * 4 + reg;
                    int n = n0 + m;
                    float iv = sigmoidf_(ai[m2][reg] + bi);
                    float fv = sigmoidf_(af[m2][reg] + bff);
                    float gv = tanhf_(ag[m2][reg] + bg);
                    float ov = sigmoidf_(ao[m2][reg] + bo);
                    float c0v = (n < N_NODES) ? c0[(size_t)n * F_INF + c] : 0.0f;
                    float cc = fv * c0v + iv * gv;
                    float hh = ov * tanhf_(cc);
                    h1v[mp][m2][reg] = hh;
                    if (n < N_NODES) {
                        c1[(size_t)n * F_INF + c] = cc;
                        h1[(size_t)n * F_INF + c] = hh;
                    }
                }
            }
        }
    }
    __syncthreads();   // A2/bias/bl dead; overlay begins

    float* h1s = (float*)smem;   // [64][65]
    {
        int c = w * 16 + ln;
#pragma unroll
        for (int mp = 0; mp < 2; ++mp)
#pragma unroll
            for (int m2 = 0; m2 < 2; ++m2)
#pragma unroll
                for (int reg = 0; reg < 4; ++reg) {
                    int m = (mp * 2 + m2) * 16 + quad * 4 + reg;
                    h1s[m * 65 + c] = h1v[mp][m2][reg];
                }
    }
    __syncthreads();

    // ---- fused head: out[n,t] = relu(h1[n,:]) @ lw^T + lb ----
    for (int o = tid; o < 512; o += 256) {
        int nl = o & 63, t = o >> 6;   // t uniform per wave-instr
        float acc = lbs[t];
        const float* hr = h1s + nl * 65;
#pragma unroll 8
        for (int k = 0; k < F_INF; ++k)
            acc += fmaxf(hr[k], 0.0f) * lwf[k * 8 + t];
        int n = n0 + nl;
        if (n < N_NODES) out[(size_t)n * T_OUT + t] = acc;
    }
}

extern "C" void kernel_launch(void* const* d_in, const int* in_sizes, int n_in,
                              void* d_out, int out_size, void* d_ws, size_t ws_size,
                              hipStream_t stream) {
    const float* x     = (const float*)d_in[0];
    const int*   ei    = (const int*)d_in[1];
    const float* ew    = (const float*)d_in[2];
    const float* h0    = (const float*)d_in[3];
    const float* c0    = (const float*)d_in[4];
    const float* ggc   = (const float*)d_in[5];
    const float* gwih  = (const float*)d_in[6];
    const float* gwhh  = (const float*)d_in[7];
    const float* gbih  = (const float*)d_in[8];
    const float* gbhh  = (const float*)d_in[9];
    const float* lwih  = (const float*)d_in[10];
    const float* lwhh  = (const float*)d_in[11];
    const float* lbih  = (const float*)d_in[12];
    const float* lbhh  = (const float*)d_in[13];
    const float* lw    = (const float*)d_in[14];
    const float* lb    = (const float*)d_in[15];

    float* out = (float*)d_out;                  // [N, 8]
    float* h1  = out + (size_t)N_NODES * T_OUT;  // [N, 64]
    float* c1  = h1 + (size_t)N_NODES * F_INF;   // [N, 64]

    // workspace layout (bytes; all 16B aligned)
    char* ws = (char*)d_ws;
    u16*   xaggbf = (u16*)ws;                          // 6,400,000
    u16*   xbf    = (u16*)(ws + 6400000);              // 6,400,000
    u16*   Wgru   = (u16*)(ws + 12800000);             // 131,072 (padded)
    u16*   Wl     = (u16*)(ws + 12931072);             // 98,304
    int2*  edge   = (int2*)(ws + 13029376);            // 6,400,000
    int*   deg    = (int*)(ws + 19429376);             // 200,000
    int*   rowptr = deg + N_NODES;                     // 200,004
    int*   cursor = rowptr + N_NODES + 1;              // 200,000

    hipMemsetAsync(deg, 0, N_NODES * sizeof(int), stream);

    k_prep<<<HIST_B + XBF_B + WP_B, 256, 0, stream>>>(
        ei, x, ggc, gwih, gwhh, lwih, lwhh, deg, xbf, Wgru, Wl);
    k_scan<<<1, SCAN_T, 0, stream>>>(deg, rowptr, cursor);
    { int b = (HALF_E + 255) / 256;
      k_reorder<<<b, 256, 0, stream>>>(ei, ew, cursor, edge); }
    { int b = (N_NODES + 3) / 4;
      k_agg<<<b, 256, 0, stream>>>(rowptr, edge, xbf, xaggbf); }
    { int b = (N_NODES + 63) / 64;  // 782
      k_fused<<<b, 256, 0, stream>>>(xaggbf, xbf, h0, c0, Wgru, Wl,
                                     gbih, gbhh, lbih, lbhh, lw, lb,
                                     out, h1, c1); }
}

// Round 9
// 337.338 us; speedup vs baseline: 1.3140x; 1.0635x over previous
//
#include <hip/hip_runtime.h>

// Problem constants (match reference setup_inputs)
#define N_NODES 50000
#define N_EDGES 800000
#define F_INF   64
#define C_CH    100
#define T_OUT   8

typedef unsigned short u16;
typedef unsigned int   u32;
typedef __attribute__((ext_vector_type(8))) short bf16x8;
typedef __attribute__((ext_vector_type(4))) float f32x4;

__device__ __forceinline__ float sigmoidf_(float x) {
    return 1.0f / (1.0f + __expf(-x));
}
__device__ __forceinline__ float tanhf_(float x) {
    return 1.0f - 2.0f / (__expf(2.0f * x) + 1.0f);
}
__device__ __forceinline__ u16 f2bf(float f) {
    union { float f; u32 u; } v; v.f = f;
    u32 u = v.u;
    u += 0x7FFF + ((u >> 16) & 1);   // RNE
    return (u16)(u >> 16);
}
__device__ __forceinline__ float bf2f(u16 h) {
    union { u32 u; float f; } v; v.u = ((u32)h) << 16;
    return v.f;
}
__device__ __forceinline__ float asf_(int i) {
    union { int i; float f; } v; v.i = i; return v.f;
}

// ---------------------------------------------------------------------------
// k_prep: fused (a) in-degree histogram, (b) x->bf16, (c) weight prep.
// Wgru padded to [4][128][128] (rows 100..127 zero) for branchless B-loads.
// ---------------------------------------------------------------------------
#define HIST_B 3125                     // 800000/256
#define XBF_B  1563                     // ceil(400000/256)
#define WGRU_ELEMS (4 * 128 * 128)      // 65536
#define WL_ELEMS   (4 * 64 * 192)       // 49152
#define WP_B  ((WGRU_ELEMS + WL_ELEMS + 255) / 256)   // 448
__global__ void k_prep(const int* __restrict__ ei, const float* __restrict__ x,
                       const float* __restrict__ ggc, const float* __restrict__ gwih,
                       const float* __restrict__ gwhh,
                       const float* __restrict__ lwih, const float* __restrict__ lwhh,
                       int* __restrict__ deg, u16* __restrict__ xbf,
                       u16* __restrict__ Wgru, u16* __restrict__ Wl) {
    int gb = blockIdx.x;
    if (gb < HIST_B) {
        int e = gb * 256 + threadIdx.x;
        if (e < N_EDGES) atomicAdd(&deg[ei[N_EDGES + e]], 1);
        return;
    }
    if (gb < HIST_B + XBF_B) {
        int idx = (gb - HIST_B) * 256 + threadIdx.x;
        if (idx >= N_NODES * F_INF / 8) return;
        float4 a = ((const float4*)x)[idx * 2];
        float4 b = ((const float4*)x)[idx * 2 + 1];
        uint4 p;
        p.x = (u32)f2bf(a.x) | ((u32)f2bf(a.y) << 16);
        p.y = (u32)f2bf(a.z) | ((u32)f2bf(a.w) << 16);
        p.z = (u32)f2bf(b.x) | ((u32)f2bf(b.y) << 16);
        p.w = (u32)f2bf(b.z) | ((u32)f2bf(b.w) << 16);
        ((uint4*)xbf)[idx] = p;
        return;
    }
    int idx = (gb - HIST_B - XBF_B) * 256 + threadIdx.x;
    if (idx < WGRU_ELEMS) {
        int g = idx >> 14;
        int r = idx & 16383;
        int c = r >> 7;            // 0..127 (valid < 100)
        int k = r & 127;
        float val = 0.0f;
        if (c < 100) {
            if (g < 3) {
                if (k < 64) {
                    const float* wr = gwih + (g * 100 + c) * 100;
                    const float* gr = ggc + k * 100;
                    float s = 0.0f;
#pragma unroll 4
                    for (int j = 0; j < 100; ++j) s += wr[j] * gr[j];
                    val = s;
                } else if (g < 2) {
                    val = gwhh[(g * 100 + c) * 100 + (k - 64)];
                }
            } else {
                if (k >= 64) val = gwhh[(200 + c) * 100 + (k - 64)];
            }
        }
        Wgru[idx] = f2bf(val);
    } else if (idx < WGRU_ELEMS + WL_ELEMS) {
        int i2 = idx - WGRU_ELEMS;
        int g = i2 / 12288;
        int r = i2 - g * 12288;
        int c = r / 192;
        int k = r - c * 192;
        int row = g * 64 + c;
        float val = 0.0f;
        if (k < 100) val = lwih[row * 100 + k];
        else if (k >= 128) val = lwhh[row * 64 + (k - 128)];
        Wl[i2] = f2bf(val);
    }
}

// ---------------------------------------------------------------------------
// CSR stage 2: exclusive prefix sum, LDS-staged coalesced loads, no spill.
// ---------------------------------------------------------------------------
#define SCAN_T 1024
#define SCAN_L 49
#define TILE   (512 * SCAN_L)   // 25088 elems
__global__ __launch_bounds__(SCAN_T) void k_scan(const int* __restrict__ deg,
                                                 int* __restrict__ rowptr,
                                                 int* __restrict__ cursor) {
    __shared__ int ld[TILE];
    __shared__ int s[SCAN_T];
    const int4* deg4 = (const int4*)deg;
    int4* ld4 = (int4*)ld;
    int t = threadIdx.x;

    for (int i = t; i < TILE / 4; i += SCAN_T) ld4[i] = deg4[i];
    __syncthreads();
    int tot = 0;
    if (t < 512) {
        int base = t * SCAN_L;
#pragma unroll 7
        for (int j = 0; j < SCAN_L; ++j) tot += ld[base + j];
    }
    __syncthreads();
    for (int i = t; i < TILE / 4; i += SCAN_T) {
        int g4 = TILE / 4 + i;
        ld4[i] = (g4 < N_NODES / 4) ? deg4[g4] : make_int4(0, 0, 0, 0);
    }
    __syncthreads();
    if (t >= 512) {
        int base = (t - 512) * SCAN_L;
#pragma unroll 7
        for (int j = 0; j < SCAN_L; ++j) tot += ld[base + j];
    }
    s[t] = tot;
    __syncthreads();
    for (int off = 1; off < SCAN_T; off <<= 1) {
        int v = (t >= off) ? s[t - off] : 0;
        __syncthreads();
        s[t] += v;
        __syncthreads();
    }
    int run = s[t] - tot;

    for (int i = t; i < TILE / 4; i += SCAN_T) ld4[i] = deg4[i];
    __syncthreads();
    if (t < 512) {
        int base = t * SCAN_L;
        for (int j = 0; j < SCAN_L; ++j) {
            int i = base + j;
            rowptr[i] = run;
            cursor[i] = run;
            run += ld[base + j];
        }
    }
    __syncthreads();
    for (int i = t; i < TILE / 4; i += SCAN_T) {
        int g4 = TILE / 4 + i;
        ld4[i] = (g4 < N_NODES / 4) ? deg4[g4] : make_int4(0, 0, 0, 0);
    }
    __syncthreads();
    if (t >= 512) {
        int base = (t - 512) * SCAN_L;
        for (int j = 0; j < SCAN_L; ++j) {
            int g = TILE + base + j;
            if (g < N_NODES) {
                rowptr[g] = run;
                cursor[g] = run;
                run += ld[base + j];
            }
        }
    }
    if (t == SCAN_T - 1) rowptr[N_NODES] = s[t];
}

// ---------------------------------------------------------------------------
// CSR stage 3: reorder, 4 edges per thread (independent chains for MLP).
// ---------------------------------------------------------------------------
#define QUART_E (N_EDGES / 4)
__global__ void k_reorder(const int* __restrict__ ei, const float* __restrict__ ew,
                          int* __restrict__ cursor, int2* __restrict__ edge) {
    int t = blockIdx.x * blockDim.x + threadIdx.x;
    if (t >= QUART_E) return;
    int e0 = t, e1 = t + QUART_E, e2 = t + 2 * QUART_E, e3 = t + 3 * QUART_E;
    int s0 = ei[e0], s1 = ei[e1], s2 = ei[e2], s3 = ei[e3];
    int d0 = ei[N_EDGES + e0], d1 = ei[N_EDGES + e1];
    int d2 = ei[N_EDGES + e2], d3 = ei[N_EDGES + e3];
    float w0 = ew[e0], w1 = ew[e1], w2 = ew[e2], w3 = ew[e3];
    int p0 = atomicAdd(&cursor[d0], 1);
    int p1 = atomicAdd(&cursor[d1], 1);
    int p2 = atomicAdd(&cursor[d2], 1);
    int p3 = atomicAdd(&cursor[d3], 1);
    union { float f; int i; } a, b, c, d;
    a.f = w0; b.f = w1; c.f = w2; d.f = w3;
    edge[p0] = make_int2(s0, a.i);
    edge[p1] = make_int2(s1, b.i);
    edge[p2] = make_int2(s2, c.i);
    edge[p3] = make_int2(s3, d.i);
}

// ---------------------------------------------------------------------------
// Aggregate: wave per node, lane = channel (bf16 rows, 128B/edge gather).
// int4 metadata (2 edges/load), 8-edge unroll -> 8 gathers in flight.
// ---------------------------------------------------------------------------
__global__ __launch_bounds__(256) void k_agg(
    const int* __restrict__ rowptr, const int2* __restrict__ edge,
    const u16* __restrict__ xbf, u16* __restrict__ xaggbf) {
    int node = blockIdx.x * 4 + (threadIdx.x >> 6);
    int lane = threadIdx.x & 63;
    if (node >= N_NODES) return;
    int e0 = rowptr[node];
    int e1 = rowptr[node + 1];
    float acc = 0.0f;
    int e = e0;
    if ((e & 1) && e < e1) {   // align for int4 loads
        int2 ed = edge[e];
        acc += bf2f(xbf[(size_t)ed.x * F_INF + lane]) * asf_(ed.y);
        ++e;
    }
    for (; e + 7 < e1; e += 8) {
        int4 p0 = *(const int4*)(edge + e);
        int4 p1 = *(const int4*)(edge + e + 2);
        int4 p2 = *(const int4*)(edge + e + 4);
        int4 p3 = *(const int4*)(edge + e + 6);
        float v0 = bf2f(xbf[(size_t)p0.x * F_INF + lane]);
        float v1 = bf2f(xbf[(size_t)p0.z * F_INF + lane]);
        float v2 = bf2f(xbf[(size_t)p1.x * F_INF + lane]);
        float v3 = bf2f(xbf[(size_t)p1.z * F_INF + lane]);
        float v4 = bf2f(xbf[(size_t)p2.x * F_INF + lane]);
        float v5 = bf2f(xbf[(size_t)p2.z * F_INF + lane]);
        float v6 = bf2f(xbf[(size_t)p3.x * F_INF + lane]);
        float v7 = bf2f(xbf[(size_t)p3.z * F_INF + lane]);
        acc += v0 * asf_(p0.y); acc += v1 * asf_(p0.w);
        acc += v2 * asf_(p1.y); acc += v3 * asf_(p1.w);
        acc += v4 * asf_(p2.y); acc += v5 * asf_(p2.w);
        acc += v6 * asf_(p3.y); acc += v7 * asf_(p3.w);
    }
    for (; e + 3 < e1; e += 4) {
        int4 p0 = *(const int4*)(edge + e);
        int4 p1 = *(const int4*)(edge + e + 2);
        float v0 = bf2f(xbf[(size_t)p0.x * F_INF + lane]);
        float v1 = bf2f(xbf[(size_t)p0.z * F_INF + lane]);
        float v2 = bf2f(xbf[(size_t)p1.x * F_INF + lane]);
        float v3 = bf2f(xbf[(size_t)p1.z * F_INF + lane]);
        acc += v0 * asf_(p0.y); acc += v1 * asf_(p0.w);
        acc += v2 * asf_(p1.y); acc += v3 * asf_(p1.w);
    }
    for (; e < e1; ++e) {
        int2 ed = edge[e];
        acc += bf2f(xbf[(size_t)ed.x * F_INF + lane]) * asf_(ed.y);
    }
    acc /= fmaxf((float)(e1 - e0), 1.0f);
    xaggbf[(size_t)node * F_INF + lane] = f2bf(acc);
}

// ---------------------------------------------------------------------------
// Fused GRU + LSTM + head via MFMA bf16.  Block = 256 thr (4 waves), 64 nodes.
// r7 structure: A1 [xagg|x] bf16 in LDS (stride 152 u16 -> b128-phase
// conflict-free), A2 in LDS (stride 216), wave-ct specialization, weights
// loaded once per block from L2.  r8 improvements kept: padded Wgru,
// direct h1/c1 stores from accumulators, stride-65 h1s + nl-major head.
// LDS: A1 @0 (19456) | A2 @19456 (27648) | bias @47104 | bl @49504 |
//      lwf @50528 | lbs @52576  => 52608 B -> 3 blocks/CU.
// ---------------------------------------------------------------------------
#define A1S 152
#define A2S 216
__global__ __launch_bounds__(256, 3) void k_fused(
    const u16* __restrict__ xaggbf, const u16* __restrict__ xbf,
    const float* __restrict__ h0, const float* __restrict__ c0,
    const u16* __restrict__ Wgru, const u16* __restrict__ Wl,
    const float* __restrict__ gbih, const float* __restrict__ gbhh,
    const float* __restrict__ lbih, const float* __restrict__ lbhh,
    const float* __restrict__ lw, const float* __restrict__ lb,
    float* __restrict__ out, float* __restrict__ h1, float* __restrict__ c1) {
    __shared__ char smem[52608];
    u16*   A1   = (u16*)(smem);
    u16*   A2   = (u16*)(smem + 19456);
    float* bias = (float*)(smem + 47104);
    float* bl   = (float*)(smem + 49504);
    float* lwf  = (float*)(smem + 50528);   // [k*8+t]
    float* lbs  = (float*)(smem + 52576);
    int tid = threadIdx.x;
    int n0 = blockIdx.x * 64;

    // ---- stage A1 cols 0..63: xagg bf16 ----
    for (int idx = tid; idx < 512; idx += 256) {
        int row = idx >> 3, ch = idx & 7;
        int n = n0 + row;
        uint4 v = make_uint4(0, 0, 0, 0);
        if (n < N_NODES) v = ((const uint4*)xaggbf)[n * 8 + ch];
        *(uint4*)(A1 + row * A1S + ch * 8) = v;
    }
    // ---- stage A1 cols 64..127: x bf16 ----
    for (int idx = tid; idx < 512; idx += 256) {
        int row = idx >> 3, ch = idx & 7;
        int n = n0 + row;
        uint4 v = make_uint4(0, 0, 0, 0);
        if (n < N_NODES) v = ((const uint4*)xbf)[n * 8 + ch];
        *(uint4*)(A1 + row * A1S + 64 + ch * 8) = v;
    }
    // ---- stage A2 cols 128..191: h0 fp32 -> bf16 ----
    for (int idx = tid; idx < 512; idx += 256) {
        int row = idx >> 3, ch = idx & 7;
        int n = n0 + row;
        uint4 p = make_uint4(0, 0, 0, 0);
        if (n < N_NODES) {
            float4 f0 = ((const float4*)h0)[n * 16 + ch * 2];
            float4 f1 = ((const float4*)h0)[n * 16 + ch * 2 + 1];
            p.x = (u32)f2bf(f0.x) | ((u32)f2bf(f0.y) << 16);
            p.y = (u32)f2bf(f0.z) | ((u32)f2bf(f0.w) << 16);
            p.z = (u32)f2bf(f1.x) | ((u32)f2bf(f1.y) << 16);
            p.w = (u32)f2bf(f1.z) | ((u32)f2bf(f1.w) << 16);
        }
        *(uint4*)((char*)A2 + row * 432 + 256 + ch * 16) = p;
    }
    // ---- zero A2 cols 100..127 ----
    for (int idx = tid; idx < 64 * 14; idx += 256) {
        int row = idx / 14, j = idx - row * 14;
        *(u32*)((char*)A2 + row * 432 + 200 + j * 4) = 0;
    }
    // ---- biases + head weights ----
    for (int idx = tid; idx < 600; idx += 256)
        bias[idx] = (idx < 300) ? gbih[idx] : gbhh[idx - 300];
    if (tid < 256) bl[tid] = lbih[tid] + lbhh[tid];
    for (int idx = tid; idx < 512; idx += 256) {
        int k = idx >> 3, t = idx & 7;
        lwf[idx] = lw[t * F_INF + k];
    }
    if (tid < 8) lbs[tid] = lb[tid];
    __syncthreads();

    int w = tid >> 6, lane = tid & 63, quad = lane >> 4, ln = lane & 15;

    // ================= GEMM1: GRU gates, wave handles ct = w, w+4 =========
    for (int ct = w; ct < 7; ct += 4) {
        f32x4 ar[4], az[4], an[4], ah[4];
#pragma unroll
        for (int mt = 0; mt < 4; ++mt) {
            ar[mt] = (f32x4){0.f, 0.f, 0.f, 0.f};
            az[mt] = ar[mt]; an[mt] = ar[mt]; ah[mt] = ar[mt];
        }
        int rb = (ct * 16 + ln) * 128 + quad * 8;   // padded 128 rows/gate
#pragma unroll
        for (int kt = 0; kt < 4; ++kt) {
            bf16x8 b0 = *(const bf16x8*)(Wgru + rb + kt * 32);
            bf16x8 b1 = *(const bf16x8*)(Wgru + 16384 + rb + kt * 32);
            bf16x8 b2 = *(const bf16x8*)(Wgru + 32768 + rb + kt * 32);
            bf16x8 b3 = *(const bf16x8*)(Wgru + 49152 + rb + kt * 32);
#pragma unroll
            for (int mt = 0; mt < 4; ++mt) {
                bf16x8 a = *(const bf16x8*)(A1 + (mt * 16 + ln) * A1S + kt * 32 + quad * 8);
                ar[mt] = __builtin_amdgcn_mfma_f32_16x16x32_bf16(a, b0, ar[mt], 0, 0, 0);
                az[mt] = __builtin_amdgcn_mfma_f32_16x16x32_bf16(a, b1, az[mt], 0, 0, 0);
                an[mt] = __builtin_amdgcn_mfma_f32_16x16x32_bf16(a, b2, an[mt], 0, 0, 0);
                ah[mt] = __builtin_amdgcn_mfma_f32_16x16x32_bf16(a, b3, ah[mt], 0, 0, 0);
            }
        }
        int c = ct * 16 + ln;
        if (c < 100) {
            float br = bias[c] + bias[300 + c];
            float bz = bias[100 + c] + bias[400 + c];
            float bn = bias[200 + c];
            float bh = bias[500 + c];
#pragma unroll
            for (int mt = 0; mt < 4; ++mt) {
#pragma unroll
                for (int reg = 0; reg < 4; ++reg) {
                    int m = mt * 16 + quad * 4 + reg;
                    float rv = sigmoidf_(ar[mt][reg] + br);
                    float zv = sigmoidf_(az[mt][reg] + bz);
                    float nv = tanhf_(an[mt][reg] + bn + rv * (ah[mt][reg] + bh));
                    float xp = (c < F_INF) ? bf2f(A1[m * A1S + 64 + c]) : 0.0f;
                    A2[m * A2S + c] = f2bf((1.0f - zv) * nv + zv * xp);
                }
            }
        }
    }
    __syncthreads();

    // ================= GEMM2: LSTM gates + epilogue + direct stores =======
    float h1v[4][4];
    {
        int ct = w;                       // 0..3
        int c = ct * 16 + ln;             // < 64
        float bi = bl[c], bff = bl[64 + c], bg = bl[128 + c], bo = bl[192 + c];
        f32x4 ai[4], af[4], ag[4], ao[4];
#pragma unroll
        for (int mt = 0; mt < 4; ++mt) {
            ai[mt] = (f32x4){0.f, 0.f, 0.f, 0.f};
            af[mt] = ai[mt]; ag[mt] = ai[mt]; ao[mt] = ai[mt];
        }
        int rb = (ct * 16 + ln) * 192 + quad * 8;
#pragma unroll
        for (int kt = 0; kt < 6; ++kt) {
            bf16x8 b0 = *(const bf16x8*)(Wl + rb + kt * 32);
            bf16x8 b1 = *(const bf16x8*)(Wl + 12288 + rb + kt * 32);
            bf16x8 b2 = *(const bf16x8*)(Wl + 2 * 12288 + rb + kt * 32);
            bf16x8 b3 = *(const bf16x8*)(Wl + 3 * 12288 + rb + kt * 32);
#pragma unroll
            for (int mt = 0; mt < 4; ++mt) {
                bf16x8 a = *(const bf16x8*)(A2 + (mt * 16 + ln) * A2S + kt * 32 + quad * 8);
                ai[mt] = __builtin_amdgcn_mfma_f32_16x16x32_bf16(a, b0, ai[mt], 0, 0, 0);
                af[mt] = __builtin_amdgcn_mfma_f32_16x16x32_bf16(a, b1, af[mt], 0, 0, 0);
                ag[mt] = __builtin_amdgcn_mfma_f32_16x16x32_bf16(a, b2, ag[mt], 0, 0, 0);
                ao[mt] = __builtin_amdgcn_mfma_f32_16x16x32_bf16(a, b3, ao[mt], 0, 0, 0);
            }
        }
#pragma unroll
        for (int mt = 0; mt < 4; ++mt) {
#pragma unroll
            for (int reg = 0; reg < 4; ++reg) {
                int m = mt * 16 + quad * 4 + reg;
                int n = n0 + m;
                float iv = sigmoidf_(ai[mt][reg] + bi);
                float fv = sigmoidf_(af[mt][reg] + bff);
                float gv = tanhf_(ag[mt][reg] + bg);
                float ov = sigmoidf_(ao[mt][reg] + bo);
                float c0v = (n < N_NODES) ? c0[(size_t)n * F_INF + c] : 0.0f;
                float cc = fv * c0v + iv * gv;
                float hh = ov * tanhf_(cc);
                h1v[mt][reg] = hh;
                if (n < N_NODES) {
                    c1[(size_t)n * F_INF + c] = cc;
                    h1[(size_t)n * F_INF + c] = hh;
                }
            }
        }
    }
    __syncthreads();   // A1/A2 dead; overlay begins

    float* h1s = (float*)smem;   // [64][65] floats = 16640 B (over A1)
    {
        int c = w * 16 + ln;
#pragma unroll
        for (int mt = 0; mt < 4; ++mt)
#pragma unroll
            for (int reg = 0; reg < 4; ++reg) {
                int m = mt * 16 + quad * 4 + reg;
                h1s[m * 65 + c] = h1v[mt][reg];
            }
    }
    __syncthreads();

    // ---- fused head: out[n,t] = relu(h1[n,:]) @ lw^T + lb ----
    for (int o = tid; o < 512; o += 256) {
        int nl = o & 63, t = o >> 6;   // t uniform per wave-instr
        float acc = lbs[t];
        const float* hr = h1s + nl * 65;
#pragma unroll 8
        for (int k = 0; k < F_INF; ++k)
            acc += fmaxf(hr[k], 0.0f) * lwf[k * 8 + t];
        int n = n0 + nl;
        if (n < N_NODES) out[(size_t)n * T_OUT + t] = acc;
    }
}

extern "C" void kernel_launch(void* const* d_in, const int* in_sizes, int n_in,
                              void* d_out, int out_size, void* d_ws, size_t ws_size,
                              hipStream_t stream) {
    const float* x     = (const float*)d_in[0];
    const int*   ei    = (const int*)d_in[1];
    const float* ew    = (const float*)d_in[2];
    const float* h0    = (const float*)d_in[3];
    const float* c0    = (const float*)d_in[4];
    const float* ggc   = (const float*)d_in[5];
    const float* gwih  = (const float*)d_in[6];
    const float* gwhh  = (const float*)d_in[7];
    const float* gbih  = (const float*)d_in[8];
    const float* gbhh  = (const float*)d_in[9];
    const float* lwih  = (const float*)d_in[10];
    const float* lwhh  = (const float*)d_in[11];
    const float* lbih  = (const float*)d_in[12];
    const float* lbhh  = (const float*)d_in[13];
    const float* lw    = (const float*)d_in[14];
    const float* lb    = (const float*)d_in[15];

    float* out = (float*)d_out;                  // [N, 8]
    float* h1  = out + (size_t)N_NODES * T_OUT;  // [N, 64]
    float* c1  = h1 + (size_t)N_NODES * F_INF;   // [N, 64]

    // workspace layout (bytes; all 16B aligned)
    char* ws = (char*)d_ws;
    u16*   xaggbf = (u16*)ws;                          // 6,400,000
    u16*   xbf    = (u16*)(ws + 6400000);              // 6,400,000
    u16*   Wgru   = (u16*)(ws + 12800000);             // 131,072 (padded)
    u16*   Wl     = (u16*)(ws + 12931072);             // 98,304
    int2*  edge   = (int2*)(ws + 13029376);            // 6,400,000
    int*   deg    = (int*)(ws + 19429376);             // 200,000
    int*   rowptr = deg + N_NODES;                     // 200,004
    int*   cursor = rowptr + N_NODES + 1;              // 200,000

    hipMemsetAsync(deg, 0, N_NODES * sizeof(int), stream);

    k_prep<<<HIST_B + XBF_B + WP_B, 256, 0, stream>>>(
        ei, x, ggc, gwih, gwhh, lwih, lwhh, deg, xbf, Wgru, Wl);
    k_scan<<<1, SCAN_T, 0, stream>>>(deg, rowptr, cursor);
    { int b = (QUART_E + 255) / 256;
      k_reorder<<<b, 256, 0, stream>>>(ei, ew, cursor, edge); }
    { int b = (N_NODES + 3) / 4;
      k_agg<<<b, 256, 0, stream>>>(rowptr, edge, xbf, xaggbf); }
    { int b = (N_NODES + 63) / 64;  // 782
      k_fused<<<b, 256, 0, stream>>>(xaggbf, xbf, h0, c0, Wgru, Wl,
                                     gbih, gbhh, lbih, lbhh, lw, lb,
                                     out, h1, c1); }
}